// Round 3
// baseline (761.897 us; speedup 1.0000x reference)
//
#include <hip/hip_runtime.h>

#define RR 32
#define R3 32768           // 32^3
#define NPTS 65536
#define NCH 64
#define NB 8

// ---------------- shared small kernels ----------------

__global__ void mean_kernel(const float* __restrict__ coords, double* __restrict__ sums) {
    int b = blockIdx.y;
    int tid = blockIdx.x * blockDim.x + threadIdx.x;
    int stride = gridDim.x * blockDim.x;
    const float* cb = coords + (size_t)b * 3 * NPTS;
    double sx = 0.0, sy = 0.0, sz = 0.0;
    for (int n = tid; n < NPTS; n += stride) {
        sx += cb[n];
        sy += cb[NPTS + n];
        sz += cb[2 * NPTS + n];
    }
    for (int off = 32; off > 0; off >>= 1) {
        sx += __shfl_down(sx, off);
        sy += __shfl_down(sy, off);
        sz += __shfl_down(sz, off);
    }
    if ((threadIdx.x & 63) == 0) {
        atomicAdd(&sums[b * 3 + 0], sx);
        atomicAdd(&sums[b * 3 + 1], sy);
        atomicAdd(&sums[b * 3 + 2], sz);
    }
}

__global__ void maxnorm_kernel(const float* __restrict__ coords,
                               const double* __restrict__ sums,
                               unsigned* __restrict__ maxbits) {
    int b = blockIdx.y;
    float mx = (float)(sums[b * 3 + 0] * (1.0 / NPTS));
    float my = (float)(sums[b * 3 + 1] * (1.0 / NPTS));
    float mz = (float)(sums[b * 3 + 2] * (1.0 / NPTS));
    int tid = blockIdx.x * blockDim.x + threadIdx.x;
    int stride = gridDim.x * blockDim.x;
    const float* cb = coords + (size_t)b * 3 * NPTS;
    float m = 0.0f;
    for (int n = tid; n < NPTS; n += stride) {
        float dx = cb[n] - mx;
        float dy = cb[NPTS + n] - my;
        float dz = cb[2 * NPTS + n] - mz;
        m = fmaxf(m, dx * dx + dy * dy + dz * dz);
    }
    for (int off = 32; off > 0; off >>= 1) {
        m = fmaxf(m, __shfl_down(m, off));
    }
    if ((threadIdx.x & 63) == 0) {
        atomicMax(&maxbits[b], __float_as_uint(m));  // m >= 0: uint order == float order
    }
}

// ---------------- sort path ----------------

// nc output + voxel id per point + histogram.
__global__ void nc_vid_kernel(const float* __restrict__ coords,
                              const double* __restrict__ sums,
                              const unsigned* __restrict__ maxbits,
                              float* __restrict__ ncout,
                              int* __restrict__ vid,
                              unsigned* __restrict__ cnt) {
    int b = blockIdx.y;
    int n = blockIdx.x * blockDim.x + threadIdx.x;
    float mx = (float)(sums[b * 3 + 0] * (1.0 / NPTS));
    float my = (float)(sums[b * 3 + 1] * (1.0 / NPTS));
    float mz = (float)(sums[b * 3 + 2] * (1.0 / NPTS));
    float denom = 2.0f * sqrtf(__uint_as_float(maxbits[b]));  // EPS = 0
    const float* cb = coords + (size_t)b * 3 * NPTS;
    float dx = cb[n] - mx;
    float dy = cb[NPTS + n] - my;
    float dz = cb[2 * NPTS + n] - mz;
    float qx = fminf(fmaxf((dx / denom + 0.5f) * 32.0f, 0.0f), 31.0f);
    float qy = fminf(fmaxf((dy / denom + 0.5f) * 32.0f, 0.0f), 31.0f);
    float qz = fminf(fmaxf((dz / denom + 0.5f) * 32.0f, 0.0f), 31.0f);
    float* nb_ = ncout + (size_t)b * 3 * NPTS;
    nb_[n] = qx;
    nb_[NPTS + n] = qy;
    nb_[2 * NPTS + n] = qz;
    int flat = ((int)rintf(qx) * RR + (int)rintf(qy)) * RR + (int)rintf(qz);
    vid[b * NPTS + n] = flat;
    atomicAdd(&cnt[b * R3 + flat], 1u);
}

// Per-batch exclusive prefix over R3 voxels. 1 block/batch, 1024 thr, 32 vals/thr.
__global__ void scan_kernel(const unsigned* __restrict__ cnt,
                            unsigned* __restrict__ off,
                            unsigned* __restrict__ cursor) {
    __shared__ unsigned ls[1024];
    int b = blockIdx.x;
    int t = threadIdx.x;
    const unsigned* c = cnt + b * R3;
    int base = t * 32;
    unsigned v[32];
    unsigned s = 0;
#pragma unroll
    for (int k = 0; k < 32; k++) {
        unsigned x = c[base + k];
        v[k] = s;           // exclusive within chunk
        s += x;
    }
    ls[t] = s;
    __syncthreads();
    for (int d = 1; d < 1024; d <<= 1) {
        unsigned x = (t >= d) ? ls[t - d] : 0u;
        __syncthreads();
        ls[t] += x;
        __syncthreads();
    }
    unsigned chunk_excl = (t == 0) ? 0u : ls[t - 1];
#pragma unroll
    for (int k = 0; k < 32; k++) {
        unsigned o = chunk_excl + v[k];
        off[b * R3 + base + k] = o;
        cursor[b * R3 + base + k] = o;
    }
}

// order[b][cursor[vid]++] = n
__global__ void scatter_idx_kernel(const int* __restrict__ vid,
                                   unsigned* __restrict__ cursor,
                                   int* __restrict__ order) {
    int b = blockIdx.y;
    int n = blockIdx.x * blockDim.x + threadIdx.x;
    int flat = vid[b * NPTS + n];
    unsigned pos = atomicAdd(&cursor[b * R3 + flat], 1u);
    order[b * NPTS + pos] = n;
}

// feats [B][C][N] -> ft [B][N][C] via 64x64 LDS tiles.
__global__ void transpose_feat_kernel(const float* __restrict__ feats,
                                      float* __restrict__ ft) {
    __shared__ float tile[64][65];
    int b  = blockIdx.y;
    int n0 = blockIdx.x * 64;
    int t  = threadIdx.x;
    const float* fb = feats + (size_t)b * NCH * NPTS + n0;
    int i  = t & 63;
    int c0 = t >> 6;
#pragma unroll
    for (int iter = 0; iter < 16; iter++) {
        int c = iter * 4 + c0;
        tile[i][c] = fb[(size_t)c * NPTS + i];
    }
    __syncthreads();
    float* dst = ft + ((size_t)b * NPTS + n0) * NCH;
    int c  = t & 63;
    int p0 = t >> 6;
#pragma unroll
    for (int iter = 0; iter < 16; iter++) {
        int p = iter * 4 + p0;
        dst[(size_t)p * NCH + c] = tile[p][c];
    }
}

// Per-voxel gather-sum-mean; transposed coalesced write to [B][C][R3].
__global__ void gather_kernel(const float* __restrict__ ft,
                              const int* __restrict__ order,
                              const unsigned* __restrict__ off,
                              const unsigned* __restrict__ cnt,
                              float* __restrict__ voxout) {
    __shared__ float tile[64][65];
    int b    = blockIdx.y;
    int v0   = blockIdx.x * 64;
    int t    = threadIdx.x;
    int wave = t >> 6;
    int lane = t & 63;

    const float* fb = ft + ((size_t)b * NPTS) * NCH + lane;
    const int* ordb = order + b * NPTS;

#pragma unroll
    for (int k = 0; k < 16; k++) {
        int vloc = wave * 16 + k;
        int v = v0 + vloc;
        unsigned start = off[b * R3 + v];
        unsigned m = cnt[b * R3 + v];
        float s0 = 0.0f, s1 = 0.0f;
        unsigned j = 0;
        for (; j + 2 <= m; j += 2) {
            int i0 = ordb[start + j];
            int i1 = ordb[start + j + 1];
            s0 += fb[(size_t)i0 * NCH];
            s1 += fb[(size_t)i1 * NCH];
        }
        if (j < m) s0 += fb[(size_t)ordb[start + j] * NCH];
        tile[vloc][lane] = (s0 + s1) / fmaxf((float)m, 1.0f);
    }
    __syncthreads();

    float* dst = voxout + (size_t)b * NCH * R3 + v0;
    int vi = t & 63;
    int c0 = t >> 6;
#pragma unroll
    for (int iter = 0; iter < 16; iter++) {
        int c = iter * 4 + c0;
        dst[(size_t)c * R3 + vi] = tile[vi][c];
    }
}

// ---------------- round-2 fallback: voxel-major atomics ----------------

__global__ void scatter_vm_kernel(const float* __restrict__ feats,
                                  const float* __restrict__ coords,
                                  const double* __restrict__ sums,
                                  const unsigned* __restrict__ maxbits,
                                  float* __restrict__ ws_vox,
                                  float* __restrict__ ncout,
                                  float* __restrict__ cnt) {
    __shared__ float tile[64][65];
    __shared__ int   sflat[64];
    int b  = blockIdx.y;
    int n0 = blockIdx.x * 64;
    int t  = threadIdx.x;
    if (t < 64) {
        int n = n0 + t;
        float mx = (float)(sums[b * 3 + 0] * (1.0 / NPTS));
        float my = (float)(sums[b * 3 + 1] * (1.0 / NPTS));
        float mz = (float)(sums[b * 3 + 2] * (1.0 / NPTS));
        float denom = 2.0f * sqrtf(__uint_as_float(maxbits[b]));
        const float* cb = coords + (size_t)b * 3 * NPTS;
        float dx = cb[n] - mx;
        float dy = cb[NPTS + n] - my;
        float dz = cb[2 * NPTS + n] - mz;
        float qx = fminf(fmaxf((dx / denom + 0.5f) * 32.0f, 0.0f), 31.0f);
        float qy = fminf(fmaxf((dy / denom + 0.5f) * 32.0f, 0.0f), 31.0f);
        float qz = fminf(fmaxf((dz / denom + 0.5f) * 32.0f, 0.0f), 31.0f);
        float* nb_ = ncout + (size_t)b * 3 * NPTS;
        nb_[n] = qx;
        nb_[NPTS + n] = qy;
        nb_[2 * NPTS + n] = qz;
        int flat = ((int)rintf(qx) * RR + (int)rintf(qy)) * RR + (int)rintf(qz);
        sflat[t] = flat;
        atomicAdd(&cnt[b * R3 + flat], 1.0f);
    }
    const float* fb = feats + (size_t)b * NCH * NPTS + n0;
    int i = t & 63;
    int c0 = t >> 6;
#pragma unroll
    for (int iter = 0; iter < 16; iter++) {
        int c = iter * 4 + c0;
        tile[i][c] = fb[(size_t)c * NPTS + i];
    }
    __syncthreads();
    int wave = t >> 6;
    int lane = t & 63;
#pragma unroll
    for (int k = 0; k < 16; k++) {
        int p = wave * 16 + k;
        float v = tile[p][lane];
        size_t base = ((size_t)b * R3 + sflat[p]) * NCH;
        atomicAdd(&ws_vox[base + lane], v);
    }
}

__global__ void normalize_t_kernel(const float* __restrict__ ws_vox,
                                   const float* __restrict__ cnt,
                                   float* __restrict__ voxout) {
    __shared__ float tile[64][65];
    __shared__ float cinv[64];
    int b  = blockIdx.y;
    int v0 = blockIdx.x * 64;
    int t  = threadIdx.x;
    if (t < 64) cinv[t] = 1.0f / fmaxf(cnt[b * R3 + v0 + t], 1.0f);
    const float* src = ws_vox + ((size_t)b * R3 + v0) * NCH;
    int c   = t & 63;
    int vi0 = t >> 6;
#pragma unroll
    for (int iter = 0; iter < 16; iter++) {
        int vi = iter * 4 + vi0;
        tile[c][vi] = src[(size_t)vi * NCH + c];
    }
    __syncthreads();
    float* dst = voxout + (size_t)b * NCH * R3 + v0;
    int vi  = t & 63;
    int cc0 = t >> 6;
#pragma unroll
    for (int iter = 0; iter < 16; iter++) {
        int cc = iter * 4 + cc0;
        dst[(size_t)cc * R3 + vi] = tile[cc][vi] * cinv[vi];
    }
}

extern "C" void kernel_launch(void* const* d_in, const int* in_sizes, int n_in,
                              void* d_out, int out_size, void* d_ws, size_t ws_size,
                              hipStream_t stream) {
    const float* feats  = (const float*)d_in[0];   // [8,64,65536]
    const float* coords = (const float*)d_in[1];   // [8,3,65536]
    float* out = (float*)d_out;
    float* voxout = out;                                   // [8,64,32768]
    float* ncout  = out + (size_t)NB * NCH * R3;           // [8,3,65536]

    double*   sums    = (double*)d_ws;
    unsigned* maxbits = (unsigned*)((char*)d_ws + 192);

    // sort-path layout
    const size_t off_cnt = 4096;
    const size_t cnt_bytes = (size_t)NB * R3 * 4;              // 1 MB
    const size_t off_off = off_cnt + cnt_bytes;
    const size_t off_cur = off_off + cnt_bytes;
    const size_t off_vid = off_cur + cnt_bytes;
    const size_t vid_bytes = (size_t)NB * NPTS * 4;            // 2 MB
    const size_t off_ord = off_vid + vid_bytes;
    const size_t off_ft  = off_ord + vid_bytes;                // 7344128, 256-aligned
    const size_t ft_bytes = (size_t)NB * NPTS * NCH * 4;       // 134 MB
    const size_t need_sort = off_ft + ft_bytes;

    // vm-path layout (round-2)
    const size_t off_vox = off_cnt + cnt_bytes;
    const size_t vox_bytes = (size_t)NB * R3 * NCH * 4;        // 64 MB
    const size_t need_vm = off_vox + vox_bytes;

    if (ws_size >= need_sort) {
        unsigned* cnt    = (unsigned*)((char*)d_ws + off_cnt);
        unsigned* off    = (unsigned*)((char*)d_ws + off_off);
        unsigned* cursor = (unsigned*)((char*)d_ws + off_cur);
        int*      vid    = (int*)((char*)d_ws + off_vid);
        int*      order  = (int*)((char*)d_ws + off_ord);
        float*    ft     = (float*)((char*)d_ws + off_ft);

        hipMemsetAsync(d_ws, 0, off_cnt + cnt_bytes, stream);  // sums, maxbits, cnt

        mean_kernel   <<<dim3(64, NB), 256, 0, stream>>>(coords, sums);
        maxnorm_kernel<<<dim3(64, NB), 256, 0, stream>>>(coords, sums, maxbits);
        nc_vid_kernel <<<dim3(NPTS / 256, NB), 256, 0, stream>>>(coords, sums, maxbits,
                                                                 ncout, vid, cnt);
        scan_kernel   <<<NB, 1024, 0, stream>>>(cnt, off, cursor);
        scatter_idx_kernel<<<dim3(NPTS / 256, NB), 256, 0, stream>>>(vid, cursor, order);
        transpose_feat_kernel<<<dim3(NPTS / 64, NB), 256, 0, stream>>>(feats, ft);
        gather_kernel <<<dim3(R3 / 64, NB), 256, 0, stream>>>(ft, order, off, cnt, voxout);
    } else if (ws_size >= need_vm) {
        float* cntf   = (float*)((char*)d_ws + off_cnt);
        float* ws_vox = (float*)((char*)d_ws + off_vox);
        hipMemsetAsync(d_ws, 0, off_cnt + cnt_bytes, stream);
        hipMemsetAsync((char*)d_ws + off_vox, 0, vox_bytes, stream);
        mean_kernel   <<<dim3(64, NB), 256, 0, stream>>>(coords, sums);
        maxnorm_kernel<<<dim3(64, NB), 256, 0, stream>>>(coords, sums, maxbits);
        scatter_vm_kernel<<<dim3(NPTS / 64, NB), 256, 0, stream>>>(
            feats, coords, sums, maxbits, ws_vox, ncout, cntf);
        normalize_t_kernel<<<dim3(R3 / 64, NB), 256, 0, stream>>>(ws_vox, cntf, voxout);
    }
}

// Round 4
// 484.106 us; speedup vs baseline: 1.5738x; 1.5738x over previous
//
#include <hip/hip_runtime.h>
#include <hip/hip_fp16.h>

#define RR 32
#define R3 32768           // 32^3
#define NPTS 65536
#define NCH 64
#define NB 8

// ---------------- small prep kernels ----------------

__global__ void mean_kernel(const float* __restrict__ coords, double* __restrict__ sums) {
    int b = blockIdx.y;
    int tid = blockIdx.x * blockDim.x + threadIdx.x;
    int stride = gridDim.x * blockDim.x;
    const float* cb = coords + (size_t)b * 3 * NPTS;
    double sx = 0.0, sy = 0.0, sz = 0.0;
    for (int n = tid; n < NPTS; n += stride) {
        sx += cb[n];
        sy += cb[NPTS + n];
        sz += cb[2 * NPTS + n];
    }
    for (int off = 32; off > 0; off >>= 1) {
        sx += __shfl_down(sx, off);
        sy += __shfl_down(sy, off);
        sz += __shfl_down(sz, off);
    }
    if ((threadIdx.x & 63) == 0) {
        atomicAdd(&sums[b * 3 + 0], sx);
        atomicAdd(&sums[b * 3 + 1], sy);
        atomicAdd(&sums[b * 3 + 2], sz);
    }
}

__global__ void maxnorm_kernel(const float* __restrict__ coords,
                               const double* __restrict__ sums,
                               unsigned* __restrict__ maxbits) {
    int b = blockIdx.y;
    float mx = (float)(sums[b * 3 + 0] * (1.0 / NPTS));
    float my = (float)(sums[b * 3 + 1] * (1.0 / NPTS));
    float mz = (float)(sums[b * 3 + 2] * (1.0 / NPTS));
    int tid = blockIdx.x * blockDim.x + threadIdx.x;
    int stride = gridDim.x * blockDim.x;
    const float* cb = coords + (size_t)b * 3 * NPTS;
    float m = 0.0f;
    for (int n = tid; n < NPTS; n += stride) {
        float dx = cb[n] - mx;
        float dy = cb[NPTS + n] - my;
        float dz = cb[2 * NPTS + n] - mz;
        m = fmaxf(m, dx * dx + dy * dy + dz * dz);
    }
    for (int off = 32; off > 0; off >>= 1) {
        m = fmaxf(m, __shfl_down(m, off));
    }
    if ((threadIdx.x & 63) == 0) {
        atomicMax(&maxbits[b], __float_as_uint(m));  // m >= 0: uint order == float order
    }
}

__global__ void nc_vid_kernel(const float* __restrict__ coords,
                              const double* __restrict__ sums,
                              const unsigned* __restrict__ maxbits,
                              float* __restrict__ ncout,
                              int* __restrict__ vid,
                              unsigned* __restrict__ cnt) {
    int b = blockIdx.y;
    int n = blockIdx.x * blockDim.x + threadIdx.x;
    float mx = (float)(sums[b * 3 + 0] * (1.0 / NPTS));
    float my = (float)(sums[b * 3 + 1] * (1.0 / NPTS));
    float mz = (float)(sums[b * 3 + 2] * (1.0 / NPTS));
    float denom = 2.0f * sqrtf(__uint_as_float(maxbits[b]));  // EPS = 0
    const float* cb = coords + (size_t)b * 3 * NPTS;
    float dx = cb[n] - mx;
    float dy = cb[NPTS + n] - my;
    float dz = cb[2 * NPTS + n] - mz;
    float qx = fminf(fmaxf((dx / denom + 0.5f) * 32.0f, 0.0f), 31.0f);
    float qy = fminf(fmaxf((dy / denom + 0.5f) * 32.0f, 0.0f), 31.0f);
    float qz = fminf(fmaxf((dz / denom + 0.5f) * 32.0f, 0.0f), 31.0f);
    float* nb_ = ncout + (size_t)b * 3 * NPTS;
    nb_[n] = qx;
    nb_[NPTS + n] = qy;
    nb_[2 * NPTS + n] = qz;
    int flat = ((int)rintf(qx) * RR + (int)rintf(qy)) * RR + (int)rintf(qz);
    vid[b * NPTS + n] = flat;
    atomicAdd(&cnt[b * R3 + flat], 1u);
}

// Per-batch exclusive prefix over R3 voxels -> cursor. 1 block/batch.
__global__ void scan_kernel(const unsigned* __restrict__ cnt,
                            unsigned* __restrict__ cursor) {
    __shared__ unsigned ls[1024];
    int b = blockIdx.x;
    int t = threadIdx.x;
    const unsigned* c = cnt + b * R3;
    int base = t * 32;
    unsigned v[32];
    unsigned s = 0;
#pragma unroll
    for (int k = 0; k < 32; k++) {
        unsigned x = c[base + k];
        v[k] = s;
        s += x;
    }
    ls[t] = s;
    __syncthreads();
    for (int d = 1; d < 1024; d <<= 1) {
        unsigned x = (t >= d) ? ls[t - d] : 0u;
        __syncthreads();
        ls[t] += x;
        __syncthreads();
    }
    unsigned chunk_excl = (t == 0) ? 0u : ls[t - 1];
#pragma unroll
    for (int k = 0; k < 32; k++) {
        cursor[b * R3 + base + k] = chunk_excl + v[k];
    }
}

// Transpose 64x64 feature tile AND scatter rows to sorted positions (fp16).
// ft layout: [B][N][C] in sorted-position order. Also emits vid_sorted.
__global__ void permute_kernel(const float* __restrict__ feats,
                               const int* __restrict__ vid,
                               unsigned* __restrict__ cursor,
                               __half* __restrict__ ft,
                               int* __restrict__ vid_sorted) {
    __shared__ float tile[64][65];
    __shared__ int spos[64];
    int b  = blockIdx.y;
    int n0 = blockIdx.x * 64;
    int t  = threadIdx.x;

    if (t < 64) {
        int flat = vid[b * NPTS + n0 + t];
        int pos = (int)atomicAdd(&cursor[b * R3 + flat], 1u);
        spos[t] = pos;
        vid_sorted[b * NPTS + pos] = flat;
    }

    const float* fb = feats + (size_t)b * NCH * NPTS + n0;
    int i  = t & 63;
    int c0 = t >> 6;
#pragma unroll
    for (int iter = 0; iter < 16; iter++) {
        int c = iter * 4 + c0;
        tile[i][c] = fb[(size_t)c * NPTS + i];
    }
    __syncthreads();

    int wave = t >> 6;
    int lane = t & 63;
    __half* fbase = ft + (size_t)b * NPTS * NCH + lane;
#pragma unroll
    for (int k = 0; k < 16; k++) {
        int p = wave * 16 + k;
        fbase[(size_t)spos[p] * NCH] = __float2half(tile[p][lane]);
    }
}

// Balanced segmented sum: each wave owns 64 consecutive sorted positions.
// Sequential 128B reads; one coalesced 256B atomicAdd per voxel-run.
__global__ void segsum_kernel(const __half* __restrict__ ft,
                              const int* __restrict__ vid_sorted,
                              float* __restrict__ ws_vox) {
    __shared__ int svid[256];
    int b    = blockIdx.y;
    int t    = threadIdx.x;
    int wave = t >> 6;
    int lane = t & 63;
    int p0   = (blockIdx.x * 4 + wave) * 64;

    svid[t] = vid_sorted[b * NPTS + p0 + lane];   // per-wave slice, no barrier needed

    const __half* fb = ft + ((size_t)b * NPTS + p0) * NCH + lane;
    float* wv = ws_vox + (size_t)b * R3 * NCH + lane;

    float s = 0.0f;
    int vcur = svid[wave * 64];
#pragma unroll 8
    for (int k = 0; k < 64; k++) {
        float val = __half2float(fb[(size_t)k * NCH]);
        s += val;
        int vnext = (k < 63) ? svid[wave * 64 + k + 1] : -1;
        if (vnext != vcur) {
            atomicAdd(wv + (size_t)vcur * NCH, s);
            s = 0.0f;
            vcur = vnext;
        }
    }
}

// ws_vox [B][R3][C] -> voxout [B][C][R3], divide by count, skip empty voxels.
__global__ void normalize_t_kernel(const float* __restrict__ ws_vox,
                                   const unsigned* __restrict__ cnt,
                                   float* __restrict__ voxout) {
    __shared__ float tile[64][65];
    __shared__ float cinv[64];
    __shared__ unsigned scnt[64];
    int b  = blockIdx.y;
    int v0 = blockIdx.x * 64;
    int t  = threadIdx.x;
    if (t < 64) {
        unsigned c = cnt[b * R3 + v0 + t];
        scnt[t] = c;
        cinv[t] = 1.0f / fmaxf((float)c, 1.0f);
    }
    __syncthreads();
    const float* src = ws_vox + ((size_t)b * R3 + v0) * NCH;
    int c = t & 63;
    int w = t >> 6;
#pragma unroll
    for (int iter = 0; iter < 16; iter++) {
        int vi = iter * 4 + w;
        tile[c][vi] = scnt[vi] ? src[(size_t)vi * NCH + c] * cinv[vi] : 0.0f;
    }
    __syncthreads();
    float* dst = voxout + (size_t)b * NCH * R3 + v0;
    int vi = t & 63;
#pragma unroll
    for (int iter = 0; iter < 16; iter++) {
        int cc = iter * 4 + w;
        dst[(size_t)cc * R3 + vi] = tile[cc][vi];
    }
}

// ---------------- fallback: round-2 voxel-major atomics ----------------

__global__ void scatter_vm_kernel(const float* __restrict__ feats,
                                  const float* __restrict__ coords,
                                  const double* __restrict__ sums,
                                  const unsigned* __restrict__ maxbits,
                                  float* __restrict__ ws_vox,
                                  float* __restrict__ ncout,
                                  float* __restrict__ cnt) {
    __shared__ float tile[64][65];
    __shared__ int   sflat[64];
    int b  = blockIdx.y;
    int n0 = blockIdx.x * 64;
    int t  = threadIdx.x;
    if (t < 64) {
        int n = n0 + t;
        float mx = (float)(sums[b * 3 + 0] * (1.0 / NPTS));
        float my = (float)(sums[b * 3 + 1] * (1.0 / NPTS));
        float mz = (float)(sums[b * 3 + 2] * (1.0 / NPTS));
        float denom = 2.0f * sqrtf(__uint_as_float(maxbits[b]));
        const float* cb = coords + (size_t)b * 3 * NPTS;
        float dx = cb[n] - mx;
        float dy = cb[NPTS + n] - my;
        float dz = cb[2 * NPTS + n] - mz;
        float qx = fminf(fmaxf((dx / denom + 0.5f) * 32.0f, 0.0f), 31.0f);
        float qy = fminf(fmaxf((dy / denom + 0.5f) * 32.0f, 0.0f), 31.0f);
        float qz = fminf(fmaxf((dz / denom + 0.5f) * 32.0f, 0.0f), 31.0f);
        float* nb_ = ncout + (size_t)b * 3 * NPTS;
        nb_[n] = qx;
        nb_[NPTS + n] = qy;
        nb_[2 * NPTS + n] = qz;
        int flat = ((int)rintf(qx) * RR + (int)rintf(qy)) * RR + (int)rintf(qz);
        sflat[t] = flat;
        atomicAdd(&cnt[b * R3 + flat], 1.0f);
    }
    const float* fb = feats + (size_t)b * NCH * NPTS + n0;
    int i = t & 63;
    int c0 = t >> 6;
#pragma unroll
    for (int iter = 0; iter < 16; iter++) {
        int c = iter * 4 + c0;
        tile[i][c] = fb[(size_t)c * NPTS + i];
    }
    __syncthreads();
    int wave = t >> 6;
    int lane = t & 63;
#pragma unroll
    for (int k = 0; k < 16; k++) {
        int p = wave * 16 + k;
        float v = tile[p][lane];
        size_t base = ((size_t)b * R3 + sflat[p]) * NCH;
        atomicAdd(&ws_vox[base + lane], v);
    }
}

__global__ void normalize_tf_kernel(const float* __restrict__ ws_vox,
                                    const float* __restrict__ cnt,
                                    float* __restrict__ voxout) {
    __shared__ float tile[64][65];
    __shared__ float cinv[64];
    int b  = blockIdx.y;
    int v0 = blockIdx.x * 64;
    int t  = threadIdx.x;
    if (t < 64) cinv[t] = 1.0f / fmaxf(cnt[b * R3 + v0 + t], 1.0f);
    __syncthreads();
    const float* src = ws_vox + ((size_t)b * R3 + v0) * NCH;
    int c = t & 63;
    int w = t >> 6;
#pragma unroll
    for (int iter = 0; iter < 16; iter++) {
        int vi = iter * 4 + w;
        tile[c][vi] = src[(size_t)vi * NCH + c] * cinv[vi];
    }
    __syncthreads();
    float* dst = voxout + (size_t)b * NCH * R3 + v0;
    int vi = t & 63;
#pragma unroll
    for (int iter = 0; iter < 16; iter++) {
        int cc = iter * 4 + w;
        dst[(size_t)cc * R3 + vi] = tile[cc][vi];
    }
}

extern "C" void kernel_launch(void* const* d_in, const int* in_sizes, int n_in,
                              void* d_out, int out_size, void* d_ws, size_t ws_size,
                              hipStream_t stream) {
    const float* feats  = (const float*)d_in[0];   // [8,64,65536]
    const float* coords = (const float*)d_in[1];   // [8,3,65536]
    float* out = (float*)d_out;
    float* voxout = out;                                   // [8,64,32768]
    float* ncout  = out + (size_t)NB * NCH * R3;           // [8,3,65536]

    double*   sums    = (double*)d_ws;
    unsigned* maxbits = (unsigned*)((char*)d_ws + 192);

    // sorted-path layout (zeroed region first, then scratch that needs no init)
    const size_t off_cnt   = 4096;
    const size_t cnt_bytes = (size_t)NB * R3 * 4;               // 1 MB
    const size_t off_vox   = off_cnt + cnt_bytes;
    const size_t vox_bytes = (size_t)NB * R3 * NCH * 4;         // 64 MB
    const size_t off_cur   = off_vox + vox_bytes;
    const size_t off_vid   = off_cur + cnt_bytes;               // cursor 1 MB
    const size_t vid_bytes = (size_t)NB * NPTS * 4;             // 2 MB
    const size_t off_vs    = off_vid + vid_bytes;
    const size_t off_ft    = off_vs + vid_bytes;
    const size_t ft_bytes  = (size_t)NB * NPTS * NCH * 2;       // 64 MB fp16
    const size_t need_sort = off_ft + ft_bytes;                 // ~134 MB

    const size_t need_vm   = off_vox + vox_bytes;               // ~65 MB

    if (ws_size >= need_sort) {
        unsigned* cnt    = (unsigned*)((char*)d_ws + off_cnt);
        float*    ws_vox = (float*)((char*)d_ws + off_vox);
        unsigned* cursor = (unsigned*)((char*)d_ws + off_cur);
        int*      vid    = (int*)((char*)d_ws + off_vid);
        int*      vid_s  = (int*)((char*)d_ws + off_vs);
        __half*   ft     = (__half*)((char*)d_ws + off_ft);

        // one contiguous memset: sums+maxbits+cnt+ws_vox
        hipMemsetAsync(d_ws, 0, off_vox + vox_bytes, stream);

        mean_kernel   <<<dim3(128, NB), 256, 0, stream>>>(coords, sums);
        maxnorm_kernel<<<dim3(128, NB), 256, 0, stream>>>(coords, sums, maxbits);
        nc_vid_kernel <<<dim3(NPTS / 256, NB), 256, 0, stream>>>(coords, sums, maxbits,
                                                                 ncout, vid, cnt);
        scan_kernel   <<<NB, 1024, 0, stream>>>(cnt, cursor);
        permute_kernel<<<dim3(NPTS / 64, NB), 256, 0, stream>>>(feats, vid, cursor, ft, vid_s);
        segsum_kernel <<<dim3(NPTS / 256, NB), 256, 0, stream>>>(ft, vid_s, ws_vox);
        normalize_t_kernel<<<dim3(R3 / 64, NB), 256, 0, stream>>>(ws_vox, cnt, voxout);
    } else if (ws_size >= need_vm) {
        float* cntf   = (float*)((char*)d_ws + off_cnt);
        float* ws_vox = (float*)((char*)d_ws + off_vox);
        hipMemsetAsync(d_ws, 0, off_vox + vox_bytes, stream);
        mean_kernel   <<<dim3(128, NB), 256, 0, stream>>>(coords, sums);
        maxnorm_kernel<<<dim3(128, NB), 256, 0, stream>>>(coords, sums, maxbits);
        scatter_vm_kernel<<<dim3(NPTS / 64, NB), 256, 0, stream>>>(
            feats, coords, sums, maxbits, ws_vox, ncout, cntf);
        normalize_tf_kernel<<<dim3(R3 / 64, NB), 256, 0, stream>>>(ws_vox, cntf, voxout);
    }
}

// Round 5
// 356.413 us; speedup vs baseline: 2.1377x; 1.3583x over previous
//
#include <hip/hip_runtime.h>
#include <hip/hip_fp16.h>

#define RR 32
#define R3 32768           // 32^3
#define NPTS 65536
#define NCH 64
#define NB 8

// ---------------- atomic-free reductions ----------------

// grid (64, NB), block 256; each block reduces 1024 points -> part[(b*64+blk)*3+axis]
__global__ void mean1_kernel(const float* __restrict__ coords, double* __restrict__ part) {
    __shared__ double ls[3][4];
    int b = blockIdx.y, blk = blockIdx.x;
    int t = threadIdx.x;
    const float* cb = coords + (size_t)b * 3 * NPTS;
    int base = blk * 1024 + t;
    double sx = 0.0, sy = 0.0, sz = 0.0;
#pragma unroll
    for (int k = 0; k < 4; k++) {
        int n = base + k * 256;
        sx += cb[n];
        sy += cb[NPTS + n];
        sz += cb[2 * NPTS + n];
    }
    for (int off = 32; off > 0; off >>= 1) {
        sx += __shfl_down(sx, off);
        sy += __shfl_down(sy, off);
        sz += __shfl_down(sz, off);
    }
    int wave = t >> 6;
    if ((t & 63) == 0) { ls[0][wave] = sx; ls[1][wave] = sy; ls[2][wave] = sz; }
    __syncthreads();
    if (t == 0) {
        part[((size_t)b * 64 + blk) * 3 + 0] = ls[0][0] + ls[0][1] + ls[0][2] + ls[0][3];
        part[((size_t)b * 64 + blk) * 3 + 1] = ls[1][0] + ls[1][1] + ls[1][2] + ls[1][3];
        part[((size_t)b * 64 + blk) * 3 + 2] = ls[2][0] + ls[2][1] + ls[2][2] + ls[2][3];
    }
}

// grid NB, block 64; combine 64 partials -> meanf[b*4+axis]
__global__ void mean2_kernel(const double* __restrict__ part, float* __restrict__ meanf) {
    int b = blockIdx.x, l = threadIdx.x;
    double sx = part[((size_t)b * 64 + l) * 3 + 0];
    double sy = part[((size_t)b * 64 + l) * 3 + 1];
    double sz = part[((size_t)b * 64 + l) * 3 + 2];
    for (int off = 32; off > 0; off >>= 1) {
        sx += __shfl_down(sx, off);
        sy += __shfl_down(sy, off);
        sz += __shfl_down(sz, off);
    }
    if (l == 0) {
        meanf[b * 4 + 0] = (float)(sx * (1.0 / NPTS));
        meanf[b * 4 + 1] = (float)(sy * (1.0 / NPTS));
        meanf[b * 4 + 2] = (float)(sz * (1.0 / NPTS));
    }
}

// grid (64, NB), block 256; partial max of squared dist -> partmax[b*64+blk]
__global__ void max1_kernel(const float* __restrict__ coords,
                            const float* __restrict__ meanf,
                            float* __restrict__ partmax) {
    __shared__ float ls[4];
    int b = blockIdx.y, blk = blockIdx.x;
    int t = threadIdx.x;
    float mx = meanf[b * 4 + 0], my = meanf[b * 4 + 1], mz = meanf[b * 4 + 2];
    const float* cb = coords + (size_t)b * 3 * NPTS;
    int base = blk * 1024 + t;
    float m = 0.0f;
#pragma unroll
    for (int k = 0; k < 4; k++) {
        int n = base + k * 256;
        float dx = cb[n] - mx;
        float dy = cb[NPTS + n] - my;
        float dz = cb[2 * NPTS + n] - mz;
        m = fmaxf(m, dx * dx + dy * dy + dz * dz);
    }
    for (int off = 32; off > 0; off >>= 1) m = fmaxf(m, __shfl_down(m, off));
    int wave = t >> 6;
    if ((t & 63) == 0) ls[wave] = m;
    __syncthreads();
    if (t == 0) partmax[b * 64 + blk] = fmaxf(fmaxf(ls[0], ls[1]), fmaxf(ls[2], ls[3]));
}

// grid NB, block 64; combine -> denom[b] = 2*sqrt(max)
__global__ void max2_kernel(const float* __restrict__ partmax, float* __restrict__ denom) {
    int b = blockIdx.x, l = threadIdx.x;
    float m = partmax[b * 64 + l];
    for (int off = 32; off > 0; off >>= 1) m = fmaxf(m, __shfl_down(m, off));
    if (l == 0) denom[b] = 2.0f * sqrtf(m);   // EPS = 0
}

// ---------------- sorted pipeline ----------------

__global__ void nc_vid_kernel(const float* __restrict__ coords,
                              const float* __restrict__ meanf,
                              const float* __restrict__ denomv,
                              float* __restrict__ ncout,
                              int* __restrict__ vid,
                              unsigned* __restrict__ cnt) {
    int b = blockIdx.y;
    int n = blockIdx.x * blockDim.x + threadIdx.x;
    float mx = meanf[b * 4 + 0], my = meanf[b * 4 + 1], mz = meanf[b * 4 + 2];
    float denom = denomv[b];
    const float* cb = coords + (size_t)b * 3 * NPTS;
    float dx = cb[n] - mx;
    float dy = cb[NPTS + n] - my;
    float dz = cb[2 * NPTS + n] - mz;
    float qx = fminf(fmaxf((dx / denom + 0.5f) * 32.0f, 0.0f), 31.0f);
    float qy = fminf(fmaxf((dy / denom + 0.5f) * 32.0f, 0.0f), 31.0f);
    float qz = fminf(fmaxf((dz / denom + 0.5f) * 32.0f, 0.0f), 31.0f);
    float* nb_ = ncout + (size_t)b * 3 * NPTS;
    nb_[n] = qx;
    nb_[NPTS + n] = qy;
    nb_[2 * NPTS + n] = qz;
    int flat = ((int)rintf(qx) * RR + (int)rintf(qy)) * RR + (int)rintf(qz);
    vid[b * NPTS + n] = flat;
    atomicAdd(&cnt[b * R3 + flat], 1u);
}

// Per-batch exclusive prefix over R3 voxels -> cursor. 1 block/batch.
__global__ void scan_kernel(const unsigned* __restrict__ cnt,
                            unsigned* __restrict__ cursor) {
    __shared__ unsigned ls[1024];
    int b = blockIdx.x;
    int t = threadIdx.x;
    const unsigned* c = cnt + b * R3;
    int base = t * 32;
    unsigned v[32];
    unsigned s = 0;
#pragma unroll
    for (int k = 0; k < 32; k++) {
        unsigned x = c[base + k];
        v[k] = s;
        s += x;
    }
    ls[t] = s;
    __syncthreads();
    for (int d = 1; d < 1024; d <<= 1) {
        unsigned x = (t >= d) ? ls[t - d] : 0u;
        __syncthreads();
        ls[t] += x;
        __syncthreads();
    }
    unsigned chunk_excl = (t == 0) ? 0u : ls[t - 1];
#pragma unroll
    for (int k = 0; k < 32; k++) {
        cursor[b * R3 + base + k] = chunk_excl + v[k];
    }
}

// Transpose 64x64 feature tile AND scatter rows to sorted positions (fp16).
__global__ void permute_kernel(const float* __restrict__ feats,
                               const int* __restrict__ vid,
                               unsigned* __restrict__ cursor,
                               __half* __restrict__ ft,
                               int* __restrict__ vid_sorted) {
    __shared__ float tile[64][65];
    __shared__ int spos[64];
    int b  = blockIdx.y;
    int n0 = blockIdx.x * 64;
    int t  = threadIdx.x;

    if (t < 64) {
        int flat = vid[b * NPTS + n0 + t];
        int pos = (int)atomicAdd(&cursor[b * R3 + flat], 1u);
        spos[t] = pos;
        vid_sorted[b * NPTS + pos] = flat;
    }

    const float* fb = feats + (size_t)b * NCH * NPTS + n0;
    int i  = t & 63;
    int c0 = t >> 6;
#pragma unroll
    for (int iter = 0; iter < 16; iter++) {
        int c = iter * 4 + c0;
        tile[i][c] = fb[(size_t)c * NPTS + i];
    }
    __syncthreads();

    int wave = t >> 6;
    int lane = t & 63;
    __half* fbase = ft + (size_t)b * NPTS * NCH + lane;
#pragma unroll
    for (int k = 0; k < 16; k++) {
        int p = wave * 16 + k;
        fbase[(size_t)spos[p] * NCH] = __float2half(tile[p][lane]);
    }
}

// Balanced segmented sum: each wave owns 64 consecutive sorted positions.
__global__ void segsum_kernel(const __half* __restrict__ ft,
                              const int* __restrict__ vid_sorted,
                              float* __restrict__ ws_vox) {
    __shared__ int svid[256];
    int b    = blockIdx.y;
    int t    = threadIdx.x;
    int wave = t >> 6;
    int lane = t & 63;
    int p0   = (blockIdx.x * 4 + wave) * 64;

    svid[t] = vid_sorted[b * NPTS + p0 + lane];

    const __half* fb = ft + ((size_t)b * NPTS + p0) * NCH + lane;
    float* wv = ws_vox + (size_t)b * R3 * NCH + lane;

    float s = 0.0f;
    int vcur = svid[wave * 64];
#pragma unroll 8
    for (int k = 0; k < 64; k++) {
        float val = __half2float(fb[(size_t)k * NCH]);
        s += val;
        int vnext = (k < 63) ? svid[wave * 64 + k + 1] : -1;
        if (vnext != vcur) {
            atomicAdd(wv + (size_t)vcur * NCH, s);
            s = 0.0f;
            vcur = vnext;
        }
    }
}

// ws_vox [B][R3][C] -> voxout [B][C][R3], divide by count, skip empty voxels.
__global__ void normalize_t_kernel(const float* __restrict__ ws_vox,
                                   const unsigned* __restrict__ cnt,
                                   float* __restrict__ voxout) {
    __shared__ float tile[64][65];
    __shared__ float cinv[64];
    __shared__ unsigned scnt[64];
    int b  = blockIdx.y;
    int v0 = blockIdx.x * 64;
    int t  = threadIdx.x;
    if (t < 64) {
        unsigned c = cnt[b * R3 + v0 + t];
        scnt[t] = c;
        cinv[t] = 1.0f / fmaxf((float)c, 1.0f);
    }
    __syncthreads();
    const float* src = ws_vox + ((size_t)b * R3 + v0) * NCH;
    int c = t & 63;
    int w = t >> 6;
#pragma unroll
    for (int iter = 0; iter < 16; iter++) {
        int vi = iter * 4 + w;
        tile[c][vi] = scnt[vi] ? src[(size_t)vi * NCH + c] * cinv[vi] : 0.0f;
    }
    __syncthreads();
    float* dst = voxout + (size_t)b * NCH * R3 + v0;
    int vi = t & 63;
#pragma unroll
    for (int iter = 0; iter < 16; iter++) {
        int cc = iter * 4 + w;
        dst[(size_t)cc * R3 + vi] = tile[cc][vi];
    }
}

// ---------------- fallback: voxel-major atomics (round-2 path) ----------------

__global__ void scatter_vm_kernel(const float* __restrict__ feats,
                                  const float* __restrict__ coords,
                                  const float* __restrict__ meanf,
                                  const float* __restrict__ denomv,
                                  float* __restrict__ ws_vox,
                                  float* __restrict__ ncout,
                                  float* __restrict__ cnt) {
    __shared__ float tile[64][65];
    __shared__ int   sflat[64];
    int b  = blockIdx.y;
    int n0 = blockIdx.x * 64;
    int t  = threadIdx.x;
    if (t < 64) {
        int n = n0 + t;
        float mx = meanf[b * 4 + 0], my = meanf[b * 4 + 1], mz = meanf[b * 4 + 2];
        float denom = denomv[b];
        const float* cb = coords + (size_t)b * 3 * NPTS;
        float dx = cb[n] - mx;
        float dy = cb[NPTS + n] - my;
        float dz = cb[2 * NPTS + n] - mz;
        float qx = fminf(fmaxf((dx / denom + 0.5f) * 32.0f, 0.0f), 31.0f);
        float qy = fminf(fmaxf((dy / denom + 0.5f) * 32.0f, 0.0f), 31.0f);
        float qz = fminf(fmaxf((dz / denom + 0.5f) * 32.0f, 0.0f), 31.0f);
        float* nb_ = ncout + (size_t)b * 3 * NPTS;
        nb_[n] = qx;
        nb_[NPTS + n] = qy;
        nb_[2 * NPTS + n] = qz;
        int flat = ((int)rintf(qx) * RR + (int)rintf(qy)) * RR + (int)rintf(qz);
        sflat[t] = flat;
        atomicAdd(&cnt[b * R3 + flat], 1.0f);
    }
    const float* fb = feats + (size_t)b * NCH * NPTS + n0;
    int i = t & 63;
    int c0 = t >> 6;
#pragma unroll
    for (int iter = 0; iter < 16; iter++) {
        int c = iter * 4 + c0;
        tile[i][c] = fb[(size_t)c * NPTS + i];
    }
    __syncthreads();
    int wave = t >> 6;
    int lane = t & 63;
#pragma unroll
    for (int k = 0; k < 16; k++) {
        int p = wave * 16 + k;
        float v = tile[p][lane];
        size_t base = ((size_t)b * R3 + sflat[p]) * NCH;
        atomicAdd(&ws_vox[base + lane], v);
    }
}

__global__ void normalize_tf_kernel(const float* __restrict__ ws_vox,
                                    const float* __restrict__ cnt,
                                    float* __restrict__ voxout) {
    __shared__ float tile[64][65];
    __shared__ float cinv[64];
    int b  = blockIdx.y;
    int v0 = blockIdx.x * 64;
    int t  = threadIdx.x;
    if (t < 64) cinv[t] = 1.0f / fmaxf(cnt[b * R3 + v0 + t], 1.0f);
    __syncthreads();
    const float* src = ws_vox + ((size_t)b * R3 + v0) * NCH;
    int c = t & 63;
    int w = t >> 6;
#pragma unroll
    for (int iter = 0; iter < 16; iter++) {
        int vi = iter * 4 + w;
        tile[c][vi] = src[(size_t)vi * NCH + c] * cinv[vi];
    }
    __syncthreads();
    float* dst = voxout + (size_t)b * NCH * R3 + v0;
    int vi = t & 63;
#pragma unroll
    for (int iter = 0; iter < 16; iter++) {
        int cc = iter * 4 + w;
        dst[(size_t)cc * R3 + vi] = tile[cc][vi];
    }
}

extern "C" void kernel_launch(void* const* d_in, const int* in_sizes, int n_in,
                              void* d_out, int out_size, void* d_ws, size_t ws_size,
                              hipStream_t stream) {
    const float* feats  = (const float*)d_in[0];   // [8,64,65536]
    const float* coords = (const float*)d_in[1];   // [8,3,65536]
    float* out = (float*)d_out;
    float* voxout = out;                                   // [8,64,32768]
    float* ncout  = out + (size_t)NB * NCH * R3;           // [8,3,65536]

    // small scratch (no zeroing needed — all plain-written before read)
    double* part    = (double*)d_ws;                               // [NB*64*3] = 12 KB
    float*  partmax = (float*)((char*)d_ws + 12544);               // [NB*64]   = 2 KB
    float*  meanf   = (float*)((char*)d_ws + 14592);               // [NB*4]
    float*  denomv  = (float*)((char*)d_ws + 14720);               // [NB]

    // zeroed region: cnt + ws_vox (contiguous)
    const size_t off_cnt   = 16384;
    const size_t cnt_bytes = (size_t)NB * R3 * 4;               // 1 MB
    const size_t off_vox   = off_cnt + cnt_bytes;
    const size_t vox_bytes = (size_t)NB * R3 * NCH * 4;         // 64 MB
    // non-zeroed big scratch
    const size_t off_cur   = off_vox + vox_bytes;
    const size_t off_vid   = off_cur + cnt_bytes;
    const size_t vid_bytes = (size_t)NB * NPTS * 4;             // 2 MB
    const size_t off_vs    = off_vid + vid_bytes;
    const size_t off_ft    = off_vs + vid_bytes;
    const size_t ft_bytes  = (size_t)NB * NPTS * NCH * 2;       // 64 MB fp16
    const size_t need_sort = off_ft + ft_bytes;                 // ~135 MB
    const size_t need_vm   = off_vox + vox_bytes;               // ~65 MB

    if (ws_size >= need_sort) {
        unsigned* cnt    = (unsigned*)((char*)d_ws + off_cnt);
        float*    ws_vox = (float*)((char*)d_ws + off_vox);
        unsigned* cursor = (unsigned*)((char*)d_ws + off_cur);
        int*      vid    = (int*)((char*)d_ws + off_vid);
        int*      vid_s  = (int*)((char*)d_ws + off_vs);
        __half*   ft     = (__half*)((char*)d_ws + off_ft);

        hipMemsetAsync((char*)d_ws + off_cnt, 0, cnt_bytes + vox_bytes, stream);

        mean1_kernel<<<dim3(64, NB), 256, 0, stream>>>(coords, part);
        mean2_kernel<<<NB, 64, 0, stream>>>(part, meanf);
        max1_kernel <<<dim3(64, NB), 256, 0, stream>>>(coords, meanf, partmax);
        max2_kernel <<<NB, 64, 0, stream>>>(partmax, denomv);
        nc_vid_kernel<<<dim3(NPTS / 256, NB), 256, 0, stream>>>(coords, meanf, denomv,
                                                                ncout, vid, cnt);
        scan_kernel  <<<NB, 1024, 0, stream>>>(cnt, cursor);
        permute_kernel<<<dim3(NPTS / 64, NB), 256, 0, stream>>>(feats, vid, cursor, ft, vid_s);
        segsum_kernel <<<dim3(NPTS / 256, NB), 256, 0, stream>>>(ft, vid_s, ws_vox);
        normalize_t_kernel<<<dim3(R3 / 64, NB), 256, 0, stream>>>(ws_vox, cnt, voxout);
    } else if (ws_size >= need_vm) {
        float* cntf   = (float*)((char*)d_ws + off_cnt);
        float* ws_vox = (float*)((char*)d_ws + off_vox);
        hipMemsetAsync((char*)d_ws + off_cnt, 0, cnt_bytes + vox_bytes, stream);
        mean1_kernel<<<dim3(64, NB), 256, 0, stream>>>(coords, part);
        mean2_kernel<<<NB, 64, 0, stream>>>(part, meanf);
        max1_kernel <<<dim3(64, NB), 256, 0, stream>>>(coords, meanf, partmax);
        max2_kernel <<<NB, 64, 0, stream>>>(partmax, denomv);
        scatter_vm_kernel<<<dim3(NPTS / 64, NB), 256, 0, stream>>>(
            feats, coords, meanf, denomv, ws_vox, ncout, cntf);
        normalize_tf_kernel<<<dim3(R3 / 64, NB), 256, 0, stream>>>(ws_vox, cntf, voxout);
    }
}